// Round 10
// baseline (443.275 us; speedup 1.0000x reference)
//
#include <hip/hip_runtime.h>

// ---------------------------------------------------------------------------
// AttentionTemporalEncoder on MI355X (gfx950)
// B=32, T=512, HIDDEN=1024, NH=16, HD=64
//
// R10 change: dispatch-count reduction (9 -> 5). Budget audit showed ~100 us
// of inter-dispatch overhead (~11 us x 9). Fused convw+xpose+initmax into
// one prep kernel (block-range branch); re-merged gemm1 q/k/v into the R3
// single-dispatch form (sec-branch epilogues, Q-scale folded). attn (R9),
// gemm2, final unchanged.
// ---------------------------------------------------------------------------

typedef _Float16 half8 __attribute__((ext_vector_type(8)));
typedef _Float16 half4 __attribute__((ext_vector_type(4)));
typedef float floatx4 __attribute__((ext_vector_type(4)));
typedef unsigned uintx2 __attribute__((ext_vector_type(2)));

#define HID 1024
#define TT 512
#define NB 32
#define QSCALE 0.1803368801111244f   /* 0.125 * log2(e) */
#define SB2 72.13475204444817f       /* 50 * log2(e)    */

__device__ __forceinline__ void gload16(const void* g, void* l) {
    __builtin_amdgcn_global_load_lds(
        (const __attribute__((address_space(1))) unsigned int*)g,
        (__attribute__((address_space(3))) unsigned int*)l, 16, 0, 0);
}

// monotone float->uint key: preserves order for atomicMax; 0 is below all keys
__device__ __forceinline__ unsigned fkey(float f) {
    unsigned u = __float_as_uint(f);
    return (u & 0x80000000u) ? ~u : (u | 0x80000000u);
}
__device__ __forceinline__ float funkey(unsigned k) {
    unsigned u = (k & 0x80000000u) ? (k ^ 0x80000000u) : ~k;
    return __uint_as_float(u);
}

// ---------------------------------------------------------------------------
// prep: blocks [0,16384) convw, [16384,32768) xpose, [32768,32896) initmax.
__global__ __launch_bounds__(256) void prep_kernel(
    const float* __restrict__ Wq, const float* __restrict__ Wk,
    const float* __restrict__ Wv, const float* __restrict__ Wo,
    _Float16* __restrict__ Wcat,
    const float* __restrict__ x, _Float16* __restrict__ xT,
    unsigned* __restrict__ omax)
{
    __shared__ float tile[32][33];
    const int bid = blockIdx.x;
    if (bid < 16384) {
        int i = bid * 256 + threadIdx.x;       // 0 .. 4M
        int sec = i >> 20;
        int off = i & ((1 << 20) - 1);
        const float* src = (sec == 0) ? Wq : (sec == 1) ? Wk
                          : (sec == 2) ? Wv : Wo;
        Wcat[i] = (_Float16)src[off];
    } else if (bid < 32768) {
        int idx = bid - 16384;                 // (16,32,32) x-fastest
        int b = idx >> 9, h0 = ((idx >> 4) & 31) * 32, t0 = (idx & 15) * 32;
        int tx = threadIdx.x & 31, ty = threadIdx.x >> 5;
        const float* xb = x + ((size_t)b * HID + h0) * TT + t0;
        for (int p = 0; p < 4; p++)
            tile[ty + 8 * p][tx] = xb[(ty + 8 * p) * TT + tx];
        __syncthreads();
        _Float16* xTb = xT + ((size_t)b * TT + t0) * HID + h0;
        for (int p = 0; p < 4; p++)
            xTb[(ty + 8 * p) * HID + tx] = (_Float16)tile[tx][ty + 8 * p];
    } else {
        omax[(bid - 32768) * 256 + threadIdx.x] = 0u;
    }
}

// ---------------------------------------------------------------------------
// GEMM mainloop: C(128x128) += A(128xK) * B^T, both row-major with K
// contiguous, lda = ldb = 1024. LDS tiles 128x64 halves, unpadded, granule
// swizzle p = g ^ (row & 7). Staging via global_load_lds width=16.
__device__ __forceinline__ void gemm_mainloop(
    const _Float16* __restrict__ Arows,   // W   + m0*1024
    const _Float16* __restrict__ Brows,   // act + n0*1024  (rows = n, cols = k)
    _Float16* aT, _Float16* bT, floatx4 acc[4][4], int tid)
{
    const int lane = tid & 63, wid = tid >> 6;
    const int l15 = lane & 15, quad = lane >> 4;
    const int wm = (wid >> 1) * 64, wn = (wid & 1) * 64;

    const int srow = lane >> 3;
    const int sg = (lane & 7) ^ srow;
    const _Float16* ga = Arows + (size_t)(wid * 32 + srow) * 1024 + sg * 8;
    const _Float16* gb = Brows + (size_t)(wid * 32 + srow) * 1024 + sg * 8;
    _Float16* la = aT + wid * 32 * 64;
    _Float16* lb = bT + wid * 32 * 64;

    const int pa = quad ^ (l15 & 7);

    for (int k0 = 0; k0 < 1024; k0 += 64) {
        for (int p = 0; p < 4; p++) {
            gload16(ga + k0 + p * 8 * 1024, la + p * 8 * 64);
            gload16(gb + k0 + p * 8 * 1024, lb + p * 8 * 64);
        }
        __syncthreads();
        for (int kk = 0; kk < 2; kk++) {
            const int pg = kk ? (pa ^ 4) : pa;
            half8 af[4], bf[4];
            for (int mi = 0; mi < 4; mi++)
                af[mi] = *(half8*)(aT + (wm + mi * 16 + l15) * 64 + pg * 8);
            for (int ni = 0; ni < 4; ni++)
                bf[ni] = *(half8*)(bT + (wn + ni * 16 + l15) * 64 + pg * 8);
            for (int mi = 0; mi < 4; mi++)
                for (int ni = 0; ni < 4; ni++)
                    acc[mi][ni] = __builtin_amdgcn_mfma_f32_16x16x32_f16(
                        af[mi], bf[ni], acc[mi][ni], 0, 0, 0);
        }
        __syncthreads();
    }
}

// gemm1 (merged): rows 0..1023 -> Q ([t][c], scaled by QSCALE), 1024..2047 ->
// K ([t][c]), 2048..3071 -> V ([c][t]). grid (4, 24, 32).
__global__ __launch_bounds__(256) void gemm1_kernel(
    const _Float16* __restrict__ Wcat,
    const float* __restrict__ bq, const float* __restrict__ bk,
    const float* __restrict__ bv,
    const _Float16* __restrict__ xT,
    _Float16* __restrict__ QT, _Float16* __restrict__ KT,
    _Float16* __restrict__ Vb)
{
    __shared__ __align__(16) char smem[34816];   // 2x16 KB tiles | 128x136 tr
    _Float16* aT = (_Float16*)smem;
    _Float16* bTl = aT + 128 * 64;

    const int tid = threadIdx.x;
    const int m0 = blockIdx.y * 128, n0 = blockIdx.x * 128, b = blockIdx.z;
    const int lane = tid & 63, wid = tid >> 6;
    const int l15 = lane & 15, quad = lane >> 4;
    const int wm = (wid >> 1) * 64, wn = (wid & 1) * 64;

    floatx4 acc[4][4] = {};
    gemm_mainloop(Wcat + (size_t)m0 * 1024,
                  xT + ((size_t)b * TT + n0) * HID,
                  aT, bTl, acc, tid);

    const int sec = m0 >> 10;          // 0=q 1=k 2=v (uniform per block)
    const int mo = m0 & 1023;

    if (sec < 2) {
        const float* bias = (sec == 0) ? bq : bk;
        _Float16* dst = (sec == 0) ? QT : KT;
        const float scale = (sec == 0) ? QSCALE : 1.0f;
        _Float16* tr = (_Float16*)smem;     // 128 x 136 halves = 34816 B
        for (int mi = 0; mi < 4; mi++) {
            float bs[4];
            for (int r = 0; r < 4; r++)
                bs[r] = bias[mo + wm + mi * 16 + quad * 4 + r];
            for (int ni = 0; ni < 4; ni++) {
                half4 pk;
                for (int r = 0; r < 4; r++)
                    pk[r] = (_Float16)((acc[mi][ni][r] + bs[r]) * scale);
                int tl = wn + ni * 16 + l15;
                int ol = wm + mi * 16 + quad * 4;
                *(half4*)(tr + tl * 136 + ol) = pk;
            }
        }
        __syncthreads();
        int tl = tid >> 1, cb = (tid & 1) * 64;
        for (int ch = 0; ch < 8; ch++) {
            uint4 v = *(uint4*)(tr + tl * 136 + cb + ch * 8);
            *(uint4*)(dst + ((size_t)b * TT + n0 + tl) * HID + mo + cb + ch * 8) = v;
        }
    } else {
        for (int mi = 0; mi < 4; mi++) {
            float bs[4];
            for (int r = 0; r < 4; r++)
                bs[r] = bv[mo + wm + mi * 16 + quad * 4 + r];
            for (int ni = 0; ni < 4; ni++) {
                int t = n0 + wn + ni * 16 + l15;
                for (int r = 0; r < 4; r++) {
                    int o = mo + wm + mi * 16 + quad * 4 + r;
                    Vb[((size_t)b * HID + o) * TT + t] =
                        (_Float16)(acc[mi][ni][r] + bs[r]);
                }
            }
        }
    }
}

// ---------------------------------------------------------------------------
// attention (R9): grid (4 q-groups, 16 heads, 32 batch); block = 256.
// 2 q-tiles per block; K/V double-buffered with prefetch-after-barrier;
// LDS fragment reads hoisted; softmax in exp2 domain.
__global__ __launch_bounds__(256) void attn_kernel(
    const _Float16* __restrict__ QT, const _Float16* __restrict__ KT,
    const _Float16* __restrict__ Vb, const int* __restrict__ mask,
    _Float16* __restrict__ OcT)
{
    __shared__ __align__(16) _Float16 kvbuf[4 * 4096];
    __shared__ __align__(16) _Float16 ps[2 * 4096];  // [qt][q][t] swizzled
    __shared__ __align__(16) float msf[2][64];       // clamp hi bound per t

    const int b = blockIdx.z, hd = blockIdx.y, q0 = blockIdx.x * 128;
    const int tid = threadIdx.x;
    const int lane = tid & 63, wid = tid >> 6;
    const int l15 = lane & 15, quad = lane >> 4;

    const _Float16* QTb = QT + ((size_t)b * TT + q0) * HID + hd * 64;
    const _Float16* KTb = KT + (size_t)b * TT * HID + hd * 64;
    const _Float16* Vbb = Vb + ((size_t)b * HID + hd * 64) * TT;
    const int* mb = mask + b * TT;

    const int srow = lane >> 3;                 // 0..7 == row&7
    const int sg = (lane & 7) ^ srow;
    const int pa = quad ^ (l15 & 7);
    const int pz = l15 & 7;

    for (int qt = 0; qt < 2; qt++)
        for (int p = 0; p < 2; p++) {
            int r = p * 32 + wid * 8 + srow;
            gload16(QTb + (size_t)(qt * 64 + r) * HID + sg * 8,
                    kvbuf + qt * 4096 + (p * 32 + wid * 8) * 64);
        }
    __syncthreads();
    half8 bq[2][2];
    for (int qt = 0; qt < 2; qt++) {
        bq[qt][0] = *(half8*)(kvbuf + qt * 4096 + (wid * 16 + l15) * 64 + pa * 8);
        bq[qt][1] = *(half8*)(kvbuf + qt * 4096 + (wid * 16 + l15) * 64 + (pa ^ 4) * 8);
    }
    __syncthreads();

    auto stage = [&](int jcn, int bufn) {
        int t0n = jcn * 64;
        _Float16* kd = kvbuf + bufn * 4096;
        _Float16* vd = kvbuf + (2 + bufn) * 4096;
        for (int p = 0; p < 2; p++) {
            int r = p * 32 + wid * 8 + srow;
            gload16(KTb + (size_t)(t0n + r) * HID + sg * 8,
                    kd + (p * 32 + wid * 8) * 64);
            gload16(Vbb + (size_t)r * TT + t0n + sg * 8,
                    vd + (p * 32 + wid * 8) * 64);
        }
        if (tid < 64) msf[bufn][tid] = mb[t0n + tid] ? SB2 : -SB2;
    };

    stage(0, 0);

    floatx4 oacc[2][4] = {};
    float rs[2] = {0.f, 0.f};
    const float lo = -SB2;

    for (int jc = 0; jc < 8; jc++) {
        const int cur = jc & 1;
        __syncthreads();
        if (jc < 7) stage(jc + 1, 1 - cur);

        const _Float16* ks = kvbuf + cur * 4096;
        const _Float16* vs = kvbuf + (2 + cur) * 4096;

        for (int jt = 0; jt < 4; jt++) {
            half8 ka0 = *(half8*)(ks + (jt * 16 + l15) * 64 + pa * 8);
            half8 ka1 = *(half8*)(ks + (jt * 16 + l15) * 64 + (pa ^ 4) * 8);
            floatx4 hi = *(floatx4*)(&msf[cur][jt * 16 + quad * 4]);
            for (int qt = 0; qt < 2; qt++) {
                floatx4 sc = {0.f, 0.f, 0.f, 0.f};
                sc = __builtin_amdgcn_mfma_f32_16x16x32_f16(ka0, bq[qt][0], sc, 0, 0, 0);
                sc = __builtin_amdgcn_mfma_f32_16x16x32_f16(ka1, bq[qt][1], sc, 0, 0, 0);
                float e0 = __builtin_amdgcn_exp2f(fminf(fmaxf(sc[0], lo), hi[0]));
                float e1 = __builtin_amdgcn_exp2f(fminf(fmaxf(sc[1], lo), hi[1]));
                float e2 = __builtin_amdgcn_exp2f(fminf(fmaxf(sc[2], lo), hi[2]));
                float e3 = __builtin_amdgcn_exp2f(fminf(fmaxf(sc[3], lo), hi[3]));
                rs[qt] += (e0 + e1) + (e2 + e3);
                unsigned uA = __builtin_bit_cast(
                    unsigned, __builtin_amdgcn_cvt_pkrtz(e0, e1));
                unsigned uB = __builtin_bit_cast(
                    unsigned, __builtin_amdgcn_cvt_pkrtz(e2, e3));
                uintx2 uv = {uA, uB};
                half4 pk = __builtin_bit_cast(half4, uv);
                int g = jt * 2 + (quad >> 1);
                *(half4*)(ps + qt * 4096 + (wid * 16 + l15) * 64 + (g ^ pz) * 8 +
                          (quad & 1) * 4) = pk;
            }
        }
        for (int kc = 0; kc < 2; kc++) {
            int g = kc * 4 + quad;
            half8 bv8[4];
            for (int d4 = 0; d4 < 4; d4++)
                bv8[d4] = *(half8*)(vs + (d4 * 16 + l15) * 64 + (g ^ pz) * 8);
            for (int qt = 0; qt < 2; qt++) {
                half8 ap = *(half8*)(ps + qt * 4096 + (wid * 16 + l15) * 64 +
                                     (g ^ pz) * 8);
                for (int d4 = 0; d4 < 4; d4++)
                    oacc[qt][d4] = __builtin_amdgcn_mfma_f32_16x16x32_f16(
                        ap, bv8[d4], oacc[qt][d4], 0, 0, 0);
            }
        }
    }

    for (int qt = 0; qt < 2; qt++) {
        float s = rs[qt];
        s += __shfl_xor(s, 16, 64);
        s += __shfl_xor(s, 32, 64);
        s = 1.0f / s;
        float inv[4];
        for (int r = 0; r < 4; r++) inv[r] = __shfl(s, quad * 4 + r, 64);
        for (int d4 = 0; d4 < 4; d4++)
            for (int r = 0; r < 4; r++) {
                int t = q0 + qt * 64 + wid * 16 + quad * 4 + r;
                int c = hd * 64 + d4 * 16 + l15;
                OcT[((size_t)b * TT + t) * HID + c] =
                    (_Float16)(oacc[qt][d4][r] * inv[r]);
            }
    }
}

// ---------------------------------------------------------------------------
// gemm2: out2 = Wo @ Oc ; epilogue: rowwise max over this block's 128 t-cols,
// atomicMax into omax (monotone key). grid (4, 8, 32)
__global__ __launch_bounds__(256) void gemm2_kernel(
    const _Float16* __restrict__ Wo16, const _Float16* __restrict__ OcT,
    unsigned* __restrict__ omax)
{
    __shared__ __align__(16) char smem[2 * 128 * 64 * 2];
    _Float16* aT = (_Float16*)smem;
    _Float16* bTl = aT + 128 * 64;

    const int tid = threadIdx.x;
    const int m0 = blockIdx.y * 128, n0 = blockIdx.x * 128, b = blockIdx.z;
    const int lane = tid & 63, wid = tid >> 6;
    const int l15 = lane & 15, quad = lane >> 4;
    const int wm = (wid >> 1) * 64;

    floatx4 acc[4][4] = {};
    gemm_mainloop(Wo16 + (size_t)m0 * 1024,
                  OcT + ((size_t)b * TT + n0) * HID,
                  aT, bTl, acc, tid);

    for (int mi = 0; mi < 4; mi++)
        for (int r = 0; r < 4; r++) {
            float v = acc[mi][0][r];
            for (int ni = 1; ni < 4; ni++) v = fmaxf(v, acc[mi][ni][r]);
            for (int d = 1; d < 16; d <<= 1) v = fmaxf(v, __shfl_xor(v, d, 64));
            if (l15 == 0) {
                int o = m0 + wm + mi * 16 + quad * 4 + r;
                atomicMax(&omax[b * HID + o], fkey(v));
            }
        }
}

__global__ __launch_bounds__(256) void final_kernel(
    const unsigned* __restrict__ omax, const float* __restrict__ bo,
    float* __restrict__ out)
{
    int i = blockIdx.x * 256 + threadIdx.x;   // 0 .. 32767
    out[i] = funkey(omax[i]) + bo[i & 1023];
}

// ---------------------------------------------------------------------------
extern "C" void kernel_launch(void* const* d_in, const int* in_sizes, int n_in,
                              void* d_out, int out_size, void* d_ws, size_t ws_size,
                              hipStream_t stream)
{
    const float* x  = (const float*)d_in[0];
    const int* mask = (const int*)d_in[1];
    const float* Wq = (const float*)d_in[2];
    const float* bq = (const float*)d_in[3];
    const float* Wk = (const float*)d_in[4];
    const float* bk = (const float*)d_in[5];
    const float* Wv = (const float*)d_in[6];
    const float* bv = (const float*)d_in[7];
    const float* Wo = (const float*)d_in[8];
    const float* bo = (const float*)d_in[9];
    float* out = (float*)d_out;

    char* ws = (char*)d_ws;
    _Float16* Wcat = (_Float16*)(ws);                      //   8 MiB (q,k,v,o)
    _Float16* xT   = (_Float16*)(ws + (8ull  << 20));      //  32 MiB
    _Float16* QT   = (_Float16*)(ws + (40ull << 20));      //  32 MiB
    _Float16* KT   = (_Float16*)(ws + (72ull << 20));      //  32 MiB
    _Float16* Vb   = (_Float16*)(ws + (104ull << 20));     //  32 MiB
    _Float16* OcT  = (_Float16*)(ws + (136ull << 20));     //  32 MiB
    unsigned* omax = (unsigned*)(ws + (168ull << 20));     // 128 KiB

    prep_kernel<<<32896, 256, 0, stream>>>(Wq, Wk, Wv, Wo, Wcat, x, xT, omax);
    gemm1_kernel<<<dim3(4, 24, 32), 256, 0, stream>>>(Wcat, bq, bk, bv, xT, QT, KT, Vb);
    attn_kernel<<<dim3(4, 16, 32), 256, 0, stream>>>(QT, KT, Vb, mask, OcT);
    gemm2_kernel<<<dim3(4, 8, 32), 256, 0, stream>>>(Wcat + (3ull << 20), OcT, omax);
    final_kernel<<<128, 256, 0, stream>>>(omax, bo, out);
}

// Round 11
// 365.212 us; speedup vs baseline: 1.2137x; 1.2137x over previous
//
#include <hip/hip_runtime.h>

// ---------------------------------------------------------------------------
// AttentionTemporalEncoder on MI355X (gfx950)
// B=32, T=512, HIDDEN=1024, NH=16, HD=64
//
// R11 change: fix R10's gemm1 regression (epilogue "*scale" -> VGPR 108->132
// -> occupancy cliff, 139->224 us). QSCALE now folded into INPUTS in prep:
// Wq section scaled during fp32->fp16 convert, bq scaled into ws buffer bqs.
// gemm1 epilogue restored byte-identical to R3 (no scale). Keeps the 5-
// dispatch structure (prep fusion validated). attn (R9), gemm2, final same.
// ---------------------------------------------------------------------------

typedef _Float16 half8 __attribute__((ext_vector_type(8)));
typedef _Float16 half4 __attribute__((ext_vector_type(4)));
typedef float floatx4 __attribute__((ext_vector_type(4)));
typedef unsigned uintx2 __attribute__((ext_vector_type(2)));

#define HID 1024
#define TT 512
#define NB 32
#define QSCALE 0.1803368801111244f   /* 0.125 * log2(e) */
#define SB2 72.13475204444817f       /* 50 * log2(e)    */

__device__ __forceinline__ void gload16(const void* g, void* l) {
    __builtin_amdgcn_global_load_lds(
        (const __attribute__((address_space(1))) unsigned int*)g,
        (__attribute__((address_space(3))) unsigned int*)l, 16, 0, 0);
}

// monotone float->uint key: preserves order for atomicMax; 0 is below all keys
__device__ __forceinline__ unsigned fkey(float f) {
    unsigned u = __float_as_uint(f);
    return (u & 0x80000000u) ? ~u : (u | 0x80000000u);
}
__device__ __forceinline__ float funkey(unsigned k) {
    unsigned u = (k & 0x80000000u) ? (k ^ 0x80000000u) : ~k;
    return __uint_as_float(u);
}

// ---------------------------------------------------------------------------
// prep: [0,16384) convw (Q section pre-scaled by QSCALE), [16384,32768) xpose,
// [32768,32896) initmax, [32896,32900) bqs = bq * QSCALE.
__global__ __launch_bounds__(256) void prep_kernel(
    const float* __restrict__ Wq, const float* __restrict__ Wk,
    const float* __restrict__ Wv, const float* __restrict__ Wo,
    _Float16* __restrict__ Wcat,
    const float* __restrict__ x, _Float16* __restrict__ xT,
    unsigned* __restrict__ omax,
    const float* __restrict__ bq, float* __restrict__ bqs)
{
    __shared__ float tile[32][33];
    const int bid = blockIdx.x;
    if (bid < 16384) {
        int i = bid * 256 + threadIdx.x;       // 0 .. 4M
        int sec = i >> 20;
        int off = i & ((1 << 20) - 1);
        const float* src = (sec == 0) ? Wq : (sec == 1) ? Wk
                          : (sec == 2) ? Wv : Wo;
        float v = src[off];
        if (sec == 0) v *= QSCALE;
        Wcat[i] = (_Float16)v;
    } else if (bid < 32768) {
        int idx = bid - 16384;                 // (16,32,32) x-fastest
        int b = idx >> 9, h0 = ((idx >> 4) & 31) * 32, t0 = (idx & 15) * 32;
        int tx = threadIdx.x & 31, ty = threadIdx.x >> 5;
        const float* xb = x + ((size_t)b * HID + h0) * TT + t0;
        for (int p = 0; p < 4; p++)
            tile[ty + 8 * p][tx] = xb[(ty + 8 * p) * TT + tx];
        __syncthreads();
        _Float16* xTb = xT + ((size_t)b * TT + t0) * HID + h0;
        for (int p = 0; p < 4; p++)
            xTb[(ty + 8 * p) * HID + tx] = (_Float16)tile[tx][ty + 8 * p];
    } else if (bid < 32896) {
        omax[(bid - 32768) * 256 + threadIdx.x] = 0u;
    } else {
        int i = (bid - 32896) * 256 + threadIdx.x;   // 0..1023
        bqs[i] = bq[i] * QSCALE;
    }
}

// ---------------------------------------------------------------------------
// GEMM mainloop: C(128x128) += A(128xK) * B^T, both row-major with K
// contiguous, lda = ldb = 1024. LDS tiles 128x64 halves, unpadded, granule
// swizzle p = g ^ (row & 7). Staging via global_load_lds width=16.
__device__ __forceinline__ void gemm_mainloop(
    const _Float16* __restrict__ Arows,   // W   + m0*1024
    const _Float16* __restrict__ Brows,   // act + n0*1024  (rows = n, cols = k)
    _Float16* aT, _Float16* bT, floatx4 acc[4][4], int tid)
{
    const int lane = tid & 63, wid = tid >> 6;
    const int l15 = lane & 15, quad = lane >> 4;
    const int wm = (wid >> 1) * 64, wn = (wid & 1) * 64;

    const int srow = lane >> 3;
    const int sg = (lane & 7) ^ srow;
    const _Float16* ga = Arows + (size_t)(wid * 32 + srow) * 1024 + sg * 8;
    const _Float16* gb = Brows + (size_t)(wid * 32 + srow) * 1024 + sg * 8;
    _Float16* la = aT + wid * 32 * 64;
    _Float16* lb = bT + wid * 32 * 64;

    const int pa = quad ^ (l15 & 7);

    for (int k0 = 0; k0 < 1024; k0 += 64) {
        for (int p = 0; p < 4; p++) {
            gload16(ga + k0 + p * 8 * 1024, la + p * 8 * 64);
            gload16(gb + k0 + p * 8 * 1024, lb + p * 8 * 64);
        }
        __syncthreads();
        for (int kk = 0; kk < 2; kk++) {
            const int pg = kk ? (pa ^ 4) : pa;
            half8 af[4], bf[4];
            for (int mi = 0; mi < 4; mi++)
                af[mi] = *(half8*)(aT + (wm + mi * 16 + l15) * 64 + pg * 8);
            for (int ni = 0; ni < 4; ni++)
                bf[ni] = *(half8*)(bT + (wn + ni * 16 + l15) * 64 + pg * 8);
            for (int mi = 0; mi < 4; mi++)
                for (int ni = 0; ni < 4; ni++)
                    acc[mi][ni] = __builtin_amdgcn_mfma_f32_16x16x32_f16(
                        af[mi], bf[ni], acc[mi][ni], 0, 0, 0);
        }
        __syncthreads();
    }
}

// gemm1 (merged, R3-identical epilogue): rows 0..1023 -> Q ([t][c]),
// 1024..2047 -> K ([t][c]), 2048..3071 -> V ([c][t]). grid (4, 24, 32).
// Q scaling lives in Wcat/bqs inputs, NOT here (R10 regression: the epilogue
// multiply pushed VGPR 108->132 and halved occupancy).
__global__ __launch_bounds__(256) void gemm1_kernel(
    const _Float16* __restrict__ Wcat,
    const float* __restrict__ bqs, const float* __restrict__ bk,
    const float* __restrict__ bv,
    const _Float16* __restrict__ xT,
    _Float16* __restrict__ QT, _Float16* __restrict__ KT,
    _Float16* __restrict__ Vb)
{
    __shared__ __align__(16) char smem[34816];   // 2x16 KB tiles | 128x136 tr
    _Float16* aT = (_Float16*)smem;
    _Float16* bTl = aT + 128 * 64;

    const int tid = threadIdx.x;
    const int m0 = blockIdx.y * 128, n0 = blockIdx.x * 128, b = blockIdx.z;
    const int lane = tid & 63, wid = tid >> 6;
    const int l15 = lane & 15, quad = lane >> 4;
    const int wm = (wid >> 1) * 64, wn = (wid & 1) * 64;

    floatx4 acc[4][4] = {};
    gemm_mainloop(Wcat + (size_t)m0 * 1024,
                  xT + ((size_t)b * TT + n0) * HID,
                  aT, bTl, acc, tid);

    const int sec = m0 >> 10;          // 0=q 1=k 2=v (uniform per block)
    const int mo = m0 & 1023;

    if (sec < 2) {
        const float* bias = (sec == 0) ? bqs : bk;
        _Float16* dst = (sec == 0) ? QT : KT;
        _Float16* tr = (_Float16*)smem;     // 128 x 136 halves = 34816 B
        for (int mi = 0; mi < 4; mi++) {
            float bs[4];
            for (int r = 0; r < 4; r++)
                bs[r] = bias[mo + wm + mi * 16 + quad * 4 + r];
            for (int ni = 0; ni < 4; ni++) {
                half4 pk;
                for (int r = 0; r < 4; r++)
                    pk[r] = (_Float16)(acc[mi][ni][r] + bs[r]);
                int tl = wn + ni * 16 + l15;
                int ol = wm + mi * 16 + quad * 4;
                *(half4*)(tr + tl * 136 + ol) = pk;
            }
        }
        __syncthreads();
        int tl = tid >> 1, cb = (tid & 1) * 64;
        for (int ch = 0; ch < 8; ch++) {
            uint4 v = *(uint4*)(tr + tl * 136 + cb + ch * 8);
            *(uint4*)(dst + ((size_t)b * TT + n0 + tl) * HID + mo + cb + ch * 8) = v;
        }
    } else {
        for (int mi = 0; mi < 4; mi++) {
            float bs[4];
            for (int r = 0; r < 4; r++)
                bs[r] = bv[mo + wm + mi * 16 + quad * 4 + r];
            for (int ni = 0; ni < 4; ni++) {
                int t = n0 + wn + ni * 16 + l15;
                for (int r = 0; r < 4; r++) {
                    int o = mo + wm + mi * 16 + quad * 4 + r;
                    Vb[((size_t)b * HID + o) * TT + t] =
                        (_Float16)(acc[mi][ni][r] + bs[r]);
                }
            }
        }
    }
}

// ---------------------------------------------------------------------------
// attention (R9): grid (4 q-groups, 16 heads, 32 batch); block = 256.
// 2 q-tiles per block; K/V double-buffered with prefetch-after-barrier;
// LDS fragment reads hoisted; softmax in exp2 domain.
__global__ __launch_bounds__(256) void attn_kernel(
    const _Float16* __restrict__ QT, const _Float16* __restrict__ KT,
    const _Float16* __restrict__ Vb, const int* __restrict__ mask,
    _Float16* __restrict__ OcT)
{
    __shared__ __align__(16) _Float16 kvbuf[4 * 4096];
    __shared__ __align__(16) _Float16 ps[2 * 4096];  // [qt][q][t] swizzled
    __shared__ __align__(16) float msf[2][64];       // clamp hi bound per t

    const int b = blockIdx.z, hd = blockIdx.y, q0 = blockIdx.x * 128;
    const int tid = threadIdx.x;
    const int lane = tid & 63, wid = tid >> 6;
    const int l15 = lane & 15, quad = lane >> 4;

    const _Float16* QTb = QT + ((size_t)b * TT + q0) * HID + hd * 64;
    const _Float16* KTb = KT + (size_t)b * TT * HID + hd * 64;
    const _Float16* Vbb = Vb + ((size_t)b * HID + hd * 64) * TT;
    const int* mb = mask + b * TT;

    const int srow = lane >> 3;                 // 0..7 == row&7
    const int sg = (lane & 7) ^ srow;
    const int pa = quad ^ (l15 & 7);
    const int pz = l15 & 7;

    for (int qt = 0; qt < 2; qt++)
        for (int p = 0; p < 2; p++) {
            int r = p * 32 + wid * 8 + srow;
            gload16(QTb + (size_t)(qt * 64 + r) * HID + sg * 8,
                    kvbuf + qt * 4096 + (p * 32 + wid * 8) * 64);
        }
    __syncthreads();
    half8 bq[2][2];
    for (int qt = 0; qt < 2; qt++) {
        bq[qt][0] = *(half8*)(kvbuf + qt * 4096 + (wid * 16 + l15) * 64 + pa * 8);
        bq[qt][1] = *(half8*)(kvbuf + qt * 4096 + (wid * 16 + l15) * 64 + (pa ^ 4) * 8);
    }
    __syncthreads();

    auto stage = [&](int jcn, int bufn) {
        int t0n = jcn * 64;
        _Float16* kd = kvbuf + bufn * 4096;
        _Float16* vd = kvbuf + (2 + bufn) * 4096;
        for (int p = 0; p < 2; p++) {
            int r = p * 32 + wid * 8 + srow;
            gload16(KTb + (size_t)(t0n + r) * HID + sg * 8,
                    kd + (p * 32 + wid * 8) * 64);
            gload16(Vbb + (size_t)r * TT + t0n + sg * 8,
                    vd + (p * 32 + wid * 8) * 64);
        }
        if (tid < 64) msf[bufn][tid] = mb[t0n + tid] ? SB2 : -SB2;
    };

    stage(0, 0);

    floatx4 oacc[2][4] = {};
    float rs[2] = {0.f, 0.f};
    const float lo = -SB2;

    for (int jc = 0; jc < 8; jc++) {
        const int cur = jc & 1;
        __syncthreads();
        if (jc < 7) stage(jc + 1, 1 - cur);

        const _Float16* ks = kvbuf + cur * 4096;
        const _Float16* vs = kvbuf + (2 + cur) * 4096;

        for (int jt = 0; jt < 4; jt++) {
            half8 ka0 = *(half8*)(ks + (jt * 16 + l15) * 64 + pa * 8);
            half8 ka1 = *(half8*)(ks + (jt * 16 + l15) * 64 + (pa ^ 4) * 8);
            floatx4 hi = *(floatx4*)(&msf[cur][jt * 16 + quad * 4]);
            for (int qt = 0; qt < 2; qt++) {
                floatx4 sc = {0.f, 0.f, 0.f, 0.f};
                sc = __builtin_amdgcn_mfma_f32_16x16x32_f16(ka0, bq[qt][0], sc, 0, 0, 0);
                sc = __builtin_amdgcn_mfma_f32_16x16x32_f16(ka1, bq[qt][1], sc, 0, 0, 0);
                float e0 = __builtin_amdgcn_exp2f(fminf(fmaxf(sc[0], lo), hi[0]));
                float e1 = __builtin_amdgcn_exp2f(fminf(fmaxf(sc[1], lo), hi[1]));
                float e2 = __builtin_amdgcn_exp2f(fminf(fmaxf(sc[2], lo), hi[2]));
                float e3 = __builtin_amdgcn_exp2f(fminf(fmaxf(sc[3], lo), hi[3]));
                rs[qt] += (e0 + e1) + (e2 + e3);
                unsigned uA = __builtin_bit_cast(
                    unsigned, __builtin_amdgcn_cvt_pkrtz(e0, e1));
                unsigned uB = __builtin_bit_cast(
                    unsigned, __builtin_amdgcn_cvt_pkrtz(e2, e3));
                uintx2 uv = {uA, uB};
                half4 pk = __builtin_bit_cast(half4, uv);
                int g = jt * 2 + (quad >> 1);
                *(half4*)(ps + qt * 4096 + (wid * 16 + l15) * 64 + (g ^ pz) * 8 +
                          (quad & 1) * 4) = pk;
            }
        }
        for (int kc = 0; kc < 2; kc++) {
            int g = kc * 4 + quad;
            half8 bv8[4];
            for (int d4 = 0; d4 < 4; d4++)
                bv8[d4] = *(half8*)(vs + (d4 * 16 + l15) * 64 + (g ^ pz) * 8);
            for (int qt = 0; qt < 2; qt++) {
                half8 ap = *(half8*)(ps + qt * 4096 + (wid * 16 + l15) * 64 +
                                     (g ^ pz) * 8);
                for (int d4 = 0; d4 < 4; d4++)
                    oacc[qt][d4] = __builtin_amdgcn_mfma_f32_16x16x32_f16(
                        ap, bv8[d4], oacc[qt][d4], 0, 0, 0);
            }
        }
    }

    for (int qt = 0; qt < 2; qt++) {
        float s = rs[qt];
        s += __shfl_xor(s, 16, 64);
        s += __shfl_xor(s, 32, 64);
        s = 1.0f / s;
        float inv[4];
        for (int r = 0; r < 4; r++) inv[r] = __shfl(s, quad * 4 + r, 64);
        for (int d4 = 0; d4 < 4; d4++)
            for (int r = 0; r < 4; r++) {
                int t = q0 + qt * 64 + wid * 16 + quad * 4 + r;
                int c = hd * 64 + d4 * 16 + l15;
                OcT[((size_t)b * TT + t) * HID + c] =
                    (_Float16)(oacc[qt][d4][r] * inv[r]);
            }
    }
}

// ---------------------------------------------------------------------------
// gemm2: out2 = Wo @ Oc ; epilogue: rowwise max over this block's 128 t-cols,
// atomicMax into omax (monotone key). grid (4, 8, 32)
__global__ __launch_bounds__(256) void gemm2_kernel(
    const _Float16* __restrict__ Wo16, const _Float16* __restrict__ OcT,
    unsigned* __restrict__ omax)
{
    __shared__ __align__(16) char smem[2 * 128 * 64 * 2];
    _Float16* aT = (_Float16*)smem;
    _Float16* bTl = aT + 128 * 64;

    const int tid = threadIdx.x;
    const int m0 = blockIdx.y * 128, n0 = blockIdx.x * 128, b = blockIdx.z;
    const int lane = tid & 63, wid = tid >> 6;
    const int l15 = lane & 15, quad = lane >> 4;
    const int wm = (wid >> 1) * 64;

    floatx4 acc[4][4] = {};
    gemm_mainloop(Wo16 + (size_t)m0 * 1024,
                  OcT + ((size_t)b * TT + n0) * HID,
                  aT, bTl, acc, tid);

    for (int mi = 0; mi < 4; mi++)
        for (int r = 0; r < 4; r++) {
            float v = acc[mi][0][r];
            for (int ni = 1; ni < 4; ni++) v = fmaxf(v, acc[mi][ni][r]);
            for (int d = 1; d < 16; d <<= 1) v = fmaxf(v, __shfl_xor(v, d, 64));
            if (l15 == 0) {
                int o = m0 + wm + mi * 16 + quad * 4 + r;
                atomicMax(&omax[b * HID + o], fkey(v));
            }
        }
}

__global__ __launch_bounds__(256) void final_kernel(
    const unsigned* __restrict__ omax, const float* __restrict__ bo,
    float* __restrict__ out)
{
    int i = blockIdx.x * 256 + threadIdx.x;   // 0 .. 32767
    out[i] = funkey(omax[i]) + bo[i & 1023];
}

// ---------------------------------------------------------------------------
extern "C" void kernel_launch(void* const* d_in, const int* in_sizes, int n_in,
                              void* d_out, int out_size, void* d_ws, size_t ws_size,
                              hipStream_t stream)
{
    const float* x  = (const float*)d_in[0];
    const int* mask = (const int*)d_in[1];
    const float* Wq = (const float*)d_in[2];
    const float* bq = (const float*)d_in[3];
    const float* Wk = (const float*)d_in[4];
    const float* bk = (const float*)d_in[5];
    const float* Wv = (const float*)d_in[6];
    const float* bv = (const float*)d_in[7];
    const float* Wo = (const float*)d_in[8];
    const float* bo = (const float*)d_in[9];
    float* out = (float*)d_out;

    char* ws = (char*)d_ws;
    _Float16* Wcat = (_Float16*)(ws);                      //   8 MiB (q,k,v,o)
    _Float16* xT   = (_Float16*)(ws + (8ull  << 20));      //  32 MiB
    _Float16* QT   = (_Float16*)(ws + (40ull << 20));      //  32 MiB
    _Float16* KT   = (_Float16*)(ws + (72ull << 20));      //  32 MiB
    _Float16* Vb   = (_Float16*)(ws + (104ull << 20));     //  32 MiB
    _Float16* OcT  = (_Float16*)(ws + (136ull << 20));     //  32 MiB
    unsigned* omax = (unsigned*)(ws + (168ull << 20));     // 128 KiB
    float*    bqs  = (float*)(ws + (168ull << 20) + (128ull << 10)); // 4 KiB

    prep_kernel<<<32900, 256, 0, stream>>>(Wq, Wk, Wv, Wo, Wcat, x, xT, omax,
                                           bq, bqs);
    gemm1_kernel<<<dim3(4, 24, 32), 256, 0, stream>>>(Wcat, bqs, bk, bv, xT, QT, KT, Vb);
    attn_kernel<<<dim3(4, 16, 32), 256, 0, stream>>>(QT, KT, Vb, mask, OcT);
    gemm2_kernel<<<dim3(4, 8, 32), 256, 0, stream>>>(Wcat + (3ull << 20), OcT, omax);
    final_kernel<<<128, 256, 0, stream>>>(omax, bo, out);
}

// Round 12
// 360.312 us; speedup vs baseline: 1.2303x; 1.0136x over previous
//
#include <hip/hip_runtime.h>

// ---------------------------------------------------------------------------
// AttentionTemporalEncoder on MI355X (gfx950)
// B=32, T=512, HIDDEN=1024, NH=16, HD=64
//
// R12 change: prep vectorization only.
//  - convw: float4 load + half4 store, 4 elems/thread (was 2-byte stores).
//  - xpose: write phase now packs half8 from padded-LDS column reads
//    (stride-33 -> 2-way bank alias = free) and does 16-B stores.
// gemm1 (R11), attn (R9), gemm2, final unchanged.
// ---------------------------------------------------------------------------

typedef _Float16 half8 __attribute__((ext_vector_type(8)));
typedef _Float16 half4 __attribute__((ext_vector_type(4)));
typedef float floatx4 __attribute__((ext_vector_type(4)));
typedef unsigned uintx2 __attribute__((ext_vector_type(2)));

#define HID 1024
#define TT 512
#define NB 32
#define QSCALE 0.1803368801111244f   /* 0.125 * log2(e) */
#define SB2 72.13475204444817f       /* 50 * log2(e)    */

__device__ __forceinline__ void gload16(const void* g, void* l) {
    __builtin_amdgcn_global_load_lds(
        (const __attribute__((address_space(1))) unsigned int*)g,
        (__attribute__((address_space(3))) unsigned int*)l, 16, 0, 0);
}

// monotone float->uint key: preserves order for atomicMax; 0 is below all keys
__device__ __forceinline__ unsigned fkey(float f) {
    unsigned u = __float_as_uint(f);
    return (u & 0x80000000u) ? ~u : (u | 0x80000000u);
}
__device__ __forceinline__ float funkey(unsigned k) {
    unsigned u = (k & 0x80000000u) ? (k ^ 0x80000000u) : ~k;
    return __uint_as_float(u);
}

// ---------------------------------------------------------------------------
// prep: [0,4096) convw (Q sec pre-scaled, float4->half4),
//       [4096,20480) xpose (half8 writes), [20480,20608) initmax,
//       [20608,20612) bqs = bq * QSCALE.
__global__ __launch_bounds__(256) void prep_kernel(
    const float* __restrict__ Wq, const float* __restrict__ Wk,
    const float* __restrict__ Wv, const float* __restrict__ Wo,
    _Float16* __restrict__ Wcat,
    const float* __restrict__ x, _Float16* __restrict__ xT,
    unsigned* __restrict__ omax,
    const float* __restrict__ bq, float* __restrict__ bqs)
{
    __shared__ float tile[32][33];
    const int bid = blockIdx.x;
    if (bid < 4096) {
        int i4 = bid * 256 + threadIdx.x;        // float4 index, 0 .. 1M
        int sec = i4 >> 18;
        int off4 = i4 & ((1 << 18) - 1);
        const float* src = (sec == 0) ? Wq : (sec == 1) ? Wk
                          : (sec == 2) ? Wv : Wo;
        float4 v = ((const float4*)src)[off4];
        if (sec == 0) {
            v.x *= QSCALE; v.y *= QSCALE; v.z *= QSCALE; v.w *= QSCALE;
        }
        half4 h = {(_Float16)v.x, (_Float16)v.y, (_Float16)v.z, (_Float16)v.w};
        *(half4*)(Wcat + (size_t)i4 * 4) = h;
    } else if (bid < 20480) {
        int idx = bid - 4096;                    // (16,32,32) x-fastest
        int b = idx >> 9, h0 = ((idx >> 4) & 31) * 32, t0 = (idx & 15) * 32;
        int tx = threadIdx.x & 31, ty = threadIdx.x >> 5;
        const float* xb = x + ((size_t)b * HID + h0) * TT + t0;
        for (int p = 0; p < 4; p++)
            tile[ty + 8 * p][tx] = xb[(ty + 8 * p) * TT + tx];  // tile[h][t]
        __syncthreads();
        if (threadIdx.x < 128) {
            int t = threadIdx.x >> 2, hc = (threadIdx.x & 3) * 8;
            half8 pk;
            for (int k = 0; k < 8; k++)
                pk[k] = (_Float16)tile[hc + k][t];
            *(half8*)(xT + ((size_t)b * TT + t0 + t) * HID + h0 + hc) = pk;
        }
    } else if (bid < 20608) {
        omax[(bid - 20480) * 256 + threadIdx.x] = 0u;
    } else {
        int i = (bid - 20608) * 256 + threadIdx.x;   // 0..1023
        bqs[i] = bq[i] * QSCALE;
    }
}

// ---------------------------------------------------------------------------
// GEMM mainloop: C(128x128) += A(128xK) * B^T, both row-major with K
// contiguous, lda = ldb = 1024. LDS tiles 128x64 halves, unpadded, granule
// swizzle p = g ^ (row & 7). Staging via global_load_lds width=16.
__device__ __forceinline__ void gemm_mainloop(
    const _Float16* __restrict__ Arows,   // W   + m0*1024
    const _Float16* __restrict__ Brows,   // act + n0*1024  (rows = n, cols = k)
    _Float16* aT, _Float16* bT, floatx4 acc[4][4], int tid)
{
    const int lane = tid & 63, wid = tid >> 6;
    const int l15 = lane & 15, quad = lane >> 4;
    const int wm = (wid >> 1) * 64, wn = (wid & 1) * 64;

    const int srow = lane >> 3;
    const int sg = (lane & 7) ^ srow;
    const _Float16* ga = Arows + (size_t)(wid * 32 + srow) * 1024 + sg * 8;
    const _Float16* gb = Brows + (size_t)(wid * 32 + srow) * 1024 + sg * 8;
    _Float16* la = aT + wid * 32 * 64;
    _Float16* lb = bT + wid * 32 * 64;

    const int pa = quad ^ (l15 & 7);

    for (int k0 = 0; k0 < 1024; k0 += 64) {
        for (int p = 0; p < 4; p++) {
            gload16(ga + k0 + p * 8 * 1024, la + p * 8 * 64);
            gload16(gb + k0 + p * 8 * 1024, lb + p * 8 * 64);
        }
        __syncthreads();
        for (int kk = 0; kk < 2; kk++) {
            const int pg = kk ? (pa ^ 4) : pa;
            half8 af[4], bf[4];
            for (int mi = 0; mi < 4; mi++)
                af[mi] = *(half8*)(aT + (wm + mi * 16 + l15) * 64 + pg * 8);
            for (int ni = 0; ni < 4; ni++)
                bf[ni] = *(half8*)(bT + (wn + ni * 16 + l15) * 64 + pg * 8);
            for (int mi = 0; mi < 4; mi++)
                for (int ni = 0; ni < 4; ni++)
                    acc[mi][ni] = __builtin_amdgcn_mfma_f32_16x16x32_f16(
                        af[mi], bf[ni], acc[mi][ni], 0, 0, 0);
        }
        __syncthreads();
    }
}

// gemm1 (merged, R3-identical epilogue): rows 0..1023 -> Q ([t][c]),
// 1024..2047 -> K ([t][c]), 2048..3071 -> V ([c][t]). grid (4, 24, 32).
// Q scaling lives in Wcat/bqs inputs, NOT here (R10 regression lesson).
__global__ __launch_bounds__(256) void gemm1_kernel(
    const _Float16* __restrict__ Wcat,
    const float* __restrict__ bqs, const float* __restrict__ bk,
    const float* __restrict__ bv,
    const _Float16* __restrict__ xT,
    _Float16* __restrict__ QT, _Float16* __restrict__ KT,
    _Float16* __restrict__ Vb)
{
    __shared__ __align__(16) char smem[34816];   // 2x16 KB tiles | 128x136 tr
    _Float16* aT = (_Float16*)smem;
    _Float16* bTl = aT + 128 * 64;

    const int tid = threadIdx.x;
    const int m0 = blockIdx.y * 128, n0 = blockIdx.x * 128, b = blockIdx.z;
    const int lane = tid & 63, wid = tid >> 6;
    const int l15 = lane & 15, quad = lane >> 4;
    const int wm = (wid >> 1) * 64, wn = (wid & 1) * 64;

    floatx4 acc[4][4] = {};
    gemm_mainloop(Wcat + (size_t)m0 * 1024,
                  xT + ((size_t)b * TT + n0) * HID,
                  aT, bTl, acc, tid);

    const int sec = m0 >> 10;          // 0=q 1=k 2=v (uniform per block)
    const int mo = m0 & 1023;

    if (sec < 2) {
        const float* bias = (sec == 0) ? bqs : bk;
        _Float16* dst = (sec == 0) ? QT : KT;
        _Float16* tr = (_Float16*)smem;     // 128 x 136 halves = 34816 B
        for (int mi = 0; mi < 4; mi++) {
            float bs[4];
            for (int r = 0; r < 4; r++)
                bs[r] = bias[mo + wm + mi * 16 + quad * 4 + r];
            for (int ni = 0; ni < 4; ni++) {
                half4 pk;
                for (int r = 0; r < 4; r++)
                    pk[r] = (_Float16)(acc[mi][ni][r] + bs[r]);
                int tl = wn + ni * 16 + l15;
                int ol = wm + mi * 16 + quad * 4;
                *(half4*)(tr + tl * 136 + ol) = pk;
            }
        }
        __syncthreads();
        int tl = tid >> 1, cb = (tid & 1) * 64;
        for (int ch = 0; ch < 8; ch++) {
            uint4 v = *(uint4*)(tr + tl * 136 + cb + ch * 8);
            *(uint4*)(dst + ((size_t)b * TT + n0 + tl) * HID + mo + cb + ch * 8) = v;
        }
    } else {
        for (int mi = 0; mi < 4; mi++) {
            float bs[4];
            for (int r = 0; r < 4; r++)
                bs[r] = bv[mo + wm + mi * 16 + quad * 4 + r];
            for (int ni = 0; ni < 4; ni++) {
                int t = n0 + wn + ni * 16 + l15;
                for (int r = 0; r < 4; r++) {
                    int o = mo + wm + mi * 16 + quad * 4 + r;
                    Vb[((size_t)b * HID + o) * TT + t] =
                        (_Float16)(acc[mi][ni][r] + bs[r]);
                }
            }
        }
    }
}

// ---------------------------------------------------------------------------
// attention (R9): grid (4 q-groups, 16 heads, 32 batch); block = 256.
// 2 q-tiles per block; K/V double-buffered with prefetch-after-barrier;
// LDS fragment reads hoisted; softmax in exp2 domain.
__global__ __launch_bounds__(256) void attn_kernel(
    const _Float16* __restrict__ QT, const _Float16* __restrict__ KT,
    const _Float16* __restrict__ Vb, const int* __restrict__ mask,
    _Float16* __restrict__ OcT)
{
    __shared__ __align__(16) _Float16 kvbuf[4 * 4096];
    __shared__ __align__(16) _Float16 ps[2 * 4096];  // [qt][q][t] swizzled
    __shared__ __align__(16) float msf[2][64];       // clamp hi bound per t

    const int b = blockIdx.z, hd = blockIdx.y, q0 = blockIdx.x * 128;
    const int tid = threadIdx.x;
    const int lane = tid & 63, wid = tid >> 6;
    const int l15 = lane & 15, quad = lane >> 4;

    const _Float16* QTb = QT + ((size_t)b * TT + q0) * HID + hd * 64;
    const _Float16* KTb = KT + (size_t)b * TT * HID + hd * 64;
    const _Float16* Vbb = Vb + ((size_t)b * HID + hd * 64) * TT;
    const int* mb = mask + b * TT;

    const int srow = lane >> 3;                 // 0..7 == row&7
    const int sg = (lane & 7) ^ srow;
    const int pa = quad ^ (l15 & 7);
    const int pz = l15 & 7;

    for (int qt = 0; qt < 2; qt++)
        for (int p = 0; p < 2; p++) {
            int r = p * 32 + wid * 8 + srow;
            gload16(QTb + (size_t)(qt * 64 + r) * HID + sg * 8,
                    kvbuf + qt * 4096 + (p * 32 + wid * 8) * 64);
        }
    __syncthreads();
    half8 bq[2][2];
    for (int qt = 0; qt < 2; qt++) {
        bq[qt][0] = *(half8*)(kvbuf + qt * 4096 + (wid * 16 + l15) * 64 + pa * 8);
        bq[qt][1] = *(half8*)(kvbuf + qt * 4096 + (wid * 16 + l15) * 64 + (pa ^ 4) * 8);
    }
    __syncthreads();

    auto stage = [&](int jcn, int bufn) {
        int t0n = jcn * 64;
        _Float16* kd = kvbuf + bufn * 4096;
        _Float16* vd = kvbuf + (2 + bufn) * 4096;
        for (int p = 0; p < 2; p++) {
            int r = p * 32 + wid * 8 + srow;
            gload16(KTb + (size_t)(t0n + r) * HID + sg * 8,
                    kd + (p * 32 + wid * 8) * 64);
            gload16(Vbb + (size_t)r * TT + t0n + sg * 8,
                    vd + (p * 32 + wid * 8) * 64);
        }
        if (tid < 64) msf[bufn][tid] = mb[t0n + tid] ? SB2 : -SB2;
    };

    stage(0, 0);

    floatx4 oacc[2][4] = {};
    float rs[2] = {0.f, 0.f};
    const float lo = -SB2;

    for (int jc = 0; jc < 8; jc++) {
        const int cur = jc & 1;
        __syncthreads();
        if (jc < 7) stage(jc + 1, 1 - cur);

        const _Float16* ks = kvbuf + cur * 4096;
        const _Float16* vs = kvbuf + (2 + cur) * 4096;

        for (int jt = 0; jt < 4; jt++) {
            half8 ka0 = *(half8*)(ks + (jt * 16 + l15) * 64 + pa * 8);
            half8 ka1 = *(half8*)(ks + (jt * 16 + l15) * 64 + (pa ^ 4) * 8);
            floatx4 hi = *(floatx4*)(&msf[cur][jt * 16 + quad * 4]);
            for (int qt = 0; qt < 2; qt++) {
                floatx4 sc = {0.f, 0.f, 0.f, 0.f};
                sc = __builtin_amdgcn_mfma_f32_16x16x32_f16(ka0, bq[qt][0], sc, 0, 0, 0);
                sc = __builtin_amdgcn_mfma_f32_16x16x32_f16(ka1, bq[qt][1], sc, 0, 0, 0);
                float e0 = __builtin_amdgcn_exp2f(fminf(fmaxf(sc[0], lo), hi[0]));
                float e1 = __builtin_amdgcn_exp2f(fminf(fmaxf(sc[1], lo), hi[1]));
                float e2 = __builtin_amdgcn_exp2f(fminf(fmaxf(sc[2], lo), hi[2]));
                float e3 = __builtin_amdgcn_exp2f(fminf(fmaxf(sc[3], lo), hi[3]));
                rs[qt] += (e0 + e1) + (e2 + e3);
                unsigned uA = __builtin_bit_cast(
                    unsigned, __builtin_amdgcn_cvt_pkrtz(e0, e1));
                unsigned uB = __builtin_bit_cast(
                    unsigned, __builtin_amdgcn_cvt_pkrtz(e2, e3));
                uintx2 uv = {uA, uB};
                half4 pk = __builtin_bit_cast(half4, uv);
                int g = jt * 2 + (quad >> 1);
                *(half4*)(ps + qt * 4096 + (wid * 16 + l15) * 64 + (g ^ pz) * 8 +
                          (quad & 1) * 4) = pk;
            }
        }
        for (int kc = 0; kc < 2; kc++) {
            int g = kc * 4 + quad;
            half8 bv8[4];
            for (int d4 = 0; d4 < 4; d4++)
                bv8[d4] = *(half8*)(vs + (d4 * 16 + l15) * 64 + (g ^ pz) * 8);
            for (int qt = 0; qt < 2; qt++) {
                half8 ap = *(half8*)(ps + qt * 4096 + (wid * 16 + l15) * 64 +
                                     (g ^ pz) * 8);
                for (int d4 = 0; d4 < 4; d4++)
                    oacc[qt][d4] = __builtin_amdgcn_mfma_f32_16x16x32_f16(
                        ap, bv8[d4], oacc[qt][d4], 0, 0, 0);
            }
        }
    }

    for (int qt = 0; qt < 2; qt++) {
        float s = rs[qt];
        s += __shfl_xor(s, 16, 64);
        s += __shfl_xor(s, 32, 64);
        s = 1.0f / s;
        float inv[4];
        for (int r = 0; r < 4; r++) inv[r] = __shfl(s, quad * 4 + r, 64);
        for (int d4 = 0; d4 < 4; d4++)
            for (int r = 0; r < 4; r++) {
                int t = q0 + qt * 64 + wid * 16 + quad * 4 + r;
                int c = hd * 64 + d4 * 16 + l15;
                OcT[((size_t)b * TT + t) * HID + c] =
                    (_Float16)(oacc[qt][d4][r] * inv[r]);
            }
    }
}

// ---------------------------------------------------------------------------
// gemm2: out2 = Wo @ Oc ; epilogue: rowwise max over this block's 128 t-cols,
// atomicMax into omax (monotone key). grid (4, 8, 32)
__global__ __launch_bounds__(256) void gemm2_kernel(
    const _Float16* __restrict__ Wo16, const _Float16* __restrict__ OcT,
    unsigned* __restrict__ omax)
{
    __shared__ __align__(16) char smem[2 * 128 * 64 * 2];
    _Float16* aT = (_Float16*)smem;
    _Float16* bTl = aT + 128 * 64;

    const int tid = threadIdx.x;
    const int m0 = blockIdx.y * 128, n0 = blockIdx.x * 128, b = blockIdx.z;
    const int lane = tid & 63, wid = tid >> 6;
    const int l15 = lane & 15, quad = lane >> 4;
    const int wm = (wid >> 1) * 64;

    floatx4 acc[4][4] = {};
    gemm_mainloop(Wo16 + (size_t)m0 * 1024,
                  OcT + ((size_t)b * TT + n0) * HID,
                  aT, bTl, acc, tid);

    for (int mi = 0; mi < 4; mi++)
        for (int r = 0; r < 4; r++) {
            float v = acc[mi][0][r];
            for (int ni = 1; ni < 4; ni++) v = fmaxf(v, acc[mi][ni][r]);
            for (int d = 1; d < 16; d <<= 1) v = fmaxf(v, __shfl_xor(v, d, 64));
            if (l15 == 0) {
                int o = m0 + wm + mi * 16 + quad * 4 + r;
                atomicMax(&omax[b * HID + o], fkey(v));
            }
        }
}

__global__ __launch_bounds__(256) void final_kernel(
    const unsigned* __restrict__ omax, const float* __restrict__ bo,
    float* __restrict__ out)
{
    int i = blockIdx.x * 256 + threadIdx.x;   // 0 .. 32767
    out[i] = funkey(omax[i]) + bo[i & 1023];
}

// ---------------------------------------------------------------------------
extern "C" void kernel_launch(void* const* d_in, const int* in_sizes, int n_in,
                              void* d_out, int out_size, void* d_ws, size_t ws_size,
                              hipStream_t stream)
{
    const float* x  = (const float*)d_in[0];
    const int* mask = (const int*)d_in[1];
    const float* Wq = (const float*)d_in[2];
    const float* bq = (const float*)d_in[3];
    const float* Wk = (const float*)d_in[4];
    const float* bk = (const float*)d_in[5];
    const float* Wv = (const float*)d_in[6];
    const float* bv = (const float*)d_in[7];
    const float* Wo = (const float*)d_in[8];
    const float* bo = (const float*)d_in[9];
    float* out = (float*)d_out;

    char* ws = (char*)d_ws;
    _Float16* Wcat = (_Float16*)(ws);                      //   8 MiB (q,k,v,o)
    _Float16* xT   = (_Float16*)(ws + (8ull  << 20));      //  32 MiB
    _Float16* QT   = (_Float16*)(ws + (40ull << 20));      //  32 MiB
    _Float16* KT   = (_Float16*)(ws + (72ull << 20));      //  32 MiB
    _Float16* Vb   = (_Float16*)(ws + (104ull << 20));     //  32 MiB
    _Float16* OcT  = (_Float16*)(ws + (136ull << 20));     //  32 MiB
    unsigned* omax = (unsigned*)(ws + (168ull << 20));     // 128 KiB
    float*    bqs  = (float*)(ws + (168ull << 20) + (128ull << 10)); // 4 KiB

    prep_kernel<<<20612, 256, 0, stream>>>(Wq, Wk, Wv, Wo, Wcat, x, xT, omax,
                                           bq, bqs);
    gemm1_kernel<<<dim3(4, 24, 32), 256, 0, stream>>>(Wcat, bqs, bk, bv, xT, QT, KT, Vb);
    attn_kernel<<<dim3(4, 16, 32), 256, 0, stream>>>(QT, KT, Vb, mask, OcT);
    gemm2_kernel<<<dim3(4, 8, 32), 256, 0, stream>>>(Wcat + (3ull << 20), OcT, omax);
    final_kernel<<<128, 256, 0, stream>>>(omax, bo, out);
}

// Round 13
// 349.091 us; speedup vs baseline: 1.2698x; 1.0321x over previous
//
#include <hip/hip_runtime.h>

// ---------------------------------------------------------------------------
// AttentionTemporalEncoder on MI355X (gfx950)
// B=32, T=512, HIDDEN=1024, NH=16, HD=64
//
// R13 change: XCD-aware block remapping (index-space only).
//  - gemm1/gemm2/attn grids flattened to 1-D, id = xcd + 8*slot, with xcd
//    chosen from the B-side tile group (n0,b) / (hd,b) so all blocks sharing
//    an xT / K/V slice run consecutively on ONE XCD -> L2 fetches it once.
//  - prep xpose: 64x64 tiles, float4 reads (256-B segments), 65-pad LDS
//    (<=2-way alias), half8 writes in 8-lane-contiguous 128-B segments.
// Hot-loop code (mainloop, attn inner) byte-identical to R12.
// ---------------------------------------------------------------------------

typedef _Float16 half8 __attribute__((ext_vector_type(8)));
typedef _Float16 half4 __attribute__((ext_vector_type(4)));
typedef float floatx4 __attribute__((ext_vector_type(4)));
typedef unsigned uintx2 __attribute__((ext_vector_type(2)));

#define HID 1024
#define TT 512
#define NB 32
#define QSCALE 0.1803368801111244f   /* 0.125 * log2(e) */
#define SB2 72.13475204444817f       /* 50 * log2(e)    */

__device__ __forceinline__ void gload16(const void* g, void* l) {
    __builtin_amdgcn_global_load_lds(
        (const __attribute__((address_space(1))) unsigned int*)g,
        (__attribute__((address_space(3))) unsigned int*)l, 16, 0, 0);
}

// monotone float->uint key: preserves order for atomicMax; 0 is below all keys
__device__ __forceinline__ unsigned fkey(float f) {
    unsigned u = __float_as_uint(f);
    return (u & 0x80000000u) ? ~u : (u | 0x80000000u);
}
__device__ __forceinline__ float funkey(unsigned k) {
    unsigned u = (k & 0x80000000u) ? (k ^ 0x80000000u) : ~k;
    return __uint_as_float(u);
}

// ---------------------------------------------------------------------------
// prep: [0,4096) convw (Q sec pre-scaled, float4->half4),
//       [4096,8192) xpose 64x64, [8192,8320) initmax, [8320,8324) bqs.
__global__ __launch_bounds__(256) void prep_kernel(
    const float* __restrict__ Wq, const float* __restrict__ Wk,
    const float* __restrict__ Wv, const float* __restrict__ Wo,
    _Float16* __restrict__ Wcat,
    const float* __restrict__ x, _Float16* __restrict__ xT,
    unsigned* __restrict__ omax,
    const float* __restrict__ bq, float* __restrict__ bqs)
{
    __shared__ float tile[64][65];
    const int bid = blockIdx.x;
    if (bid < 4096) {
        int i4 = bid * 256 + threadIdx.x;        // float4 index, 0 .. 1M
        int sec = i4 >> 18;
        int off4 = i4 & ((1 << 18) - 1);
        const float* src = (sec == 0) ? Wq : (sec == 1) ? Wk
                          : (sec == 2) ? Wv : Wo;
        float4 v = ((const float4*)src)[off4];
        if (sec == 0) {
            v.x *= QSCALE; v.y *= QSCALE; v.z *= QSCALE; v.w *= QSCALE;
        }
        half4 h = {(_Float16)v.x, (_Float16)v.y, (_Float16)v.z, (_Float16)v.w};
        *(half4*)(Wcat + (size_t)i4 * 4) = h;
    } else if (bid < 8192) {
        int idx = bid - 4096;                    // 32 b x 16 h-tiles x 8 t-tiles
        int b = idx >> 7, h0 = ((idx >> 3) & 15) * 64, t0 = (idx & 7) * 64;
        int tx = threadIdx.x & 15, ty = threadIdx.x >> 4;   // 16x16
        const float* xb = x + ((size_t)b * HID + h0) * TT + t0;
        for (int p = 0; p < 4; p++) {
            int r = ty + 16 * p;
            float4 v = *(const float4*)(xb + (size_t)r * TT + tx * 4);
            tile[r][tx * 4 + 0] = v.x;
            tile[r][tx * 4 + 1] = v.y;
            tile[r][tx * 4 + 2] = v.z;
            tile[r][tx * 4 + 3] = v.w;
        }
        __syncthreads();
        int hc = (threadIdx.x & 7) * 8, tb = threadIdx.x >> 3;  // 8 x 32
        for (int rd = 0; rd < 2; rd++) {
            int tt = tb + 32 * rd;
            half8 pk;
            for (int k = 0; k < 8; k++)
                pk[k] = (_Float16)tile[hc + k][tt];
            *(half8*)(xT + ((size_t)b * TT + t0 + tt) * HID + h0 + hc) = pk;
        }
    } else if (bid < 8320) {
        omax[(bid - 8192) * 256 + threadIdx.x] = 0u;
    } else {
        int i = (bid - 8320) * 256 + threadIdx.x;   // 0..1023
        bqs[i] = bq[i] * QSCALE;
    }
}

// ---------------------------------------------------------------------------
// GEMM mainloop: C(128x128) += A(128xK) * B^T, both row-major with K
// contiguous, lda = ldb = 1024. LDS tiles 128x64 halves, unpadded, granule
// swizzle p = g ^ (row & 7). Staging via global_load_lds width=16.
__device__ __forceinline__ void gemm_mainloop(
    const _Float16* __restrict__ Arows,   // W   + m0*1024
    const _Float16* __restrict__ Brows,   // act + n0*1024  (rows = n, cols = k)
    _Float16* aT, _Float16* bT, floatx4 acc[4][4], int tid)
{
    const int lane = tid & 63, wid = tid >> 6;
    const int l15 = lane & 15, quad = lane >> 4;
    const int wm = (wid >> 1) * 64, wn = (wid & 1) * 64;

    const int srow = lane >> 3;
    const int sg = (lane & 7) ^ srow;
    const _Float16* ga = Arows + (size_t)(wid * 32 + srow) * 1024 + sg * 8;
    const _Float16* gb = Brows + (size_t)(wid * 32 + srow) * 1024 + sg * 8;
    _Float16* la = aT + wid * 32 * 64;
    _Float16* lb = bT + wid * 32 * 64;

    const int pa = quad ^ (l15 & 7);

    for (int k0 = 0; k0 < 1024; k0 += 64) {
        for (int p = 0; p < 4; p++) {
            gload16(ga + k0 + p * 8 * 1024, la + p * 8 * 64);
            gload16(gb + k0 + p * 8 * 1024, lb + p * 8 * 64);
        }
        __syncthreads();
        for (int kk = 0; kk < 2; kk++) {
            const int pg = kk ? (pa ^ 4) : pa;
            half8 af[4], bf[4];
            for (int mi = 0; mi < 4; mi++)
                af[mi] = *(half8*)(aT + (wm + mi * 16 + l15) * 64 + pg * 8);
            for (int ni = 0; ni < 4; ni++)
                bf[ni] = *(half8*)(bT + (wn + ni * 16 + l15) * 64 + pg * 8);
            for (int mi = 0; mi < 4; mi++)
                for (int ni = 0; ni < 4; ni++)
                    acc[mi][ni] = __builtin_amdgcn_mfma_f32_16x16x32_f16(
                        af[mi], bf[ni], acc[mi][ni], 0, 0, 0);
        }
        __syncthreads();
    }
}

// gemm1 (merged, R3-identical epilogue). 1-D grid 3072, XCD-clustered:
// id = xcd + 8*slot; group grp = (n0,b) pinned to xcd = grp%8; m0 inner.
__global__ __launch_bounds__(256) void gemm1_kernel(
    const _Float16* __restrict__ Wcat,
    const float* __restrict__ bqs, const float* __restrict__ bk,
    const float* __restrict__ bv,
    const _Float16* __restrict__ xT,
    _Float16* __restrict__ QT, _Float16* __restrict__ KT,
    _Float16* __restrict__ Vb)
{
    __shared__ __align__(16) char smem[34816];   // 2x16 KB tiles | 128x136 tr
    _Float16* aT = (_Float16*)smem;
    _Float16* bTl = aT + 128 * 64;

    const int tid = threadIdx.x;
    const int id = blockIdx.x;
    const int xcd = id & 7, slot = id >> 3;      // slot 0..383
    const int grp = xcd + 8 * (slot / 24);       // 0..127 = n0i + 4*b
    const int m0 = (slot % 24) * 128;
    const int n0 = (grp & 3) * 128;
    const int b = grp >> 2;
    const int lane = tid & 63, wid = tid >> 6;
    const int l15 = lane & 15, quad = lane >> 4;
    const int wm = (wid >> 1) * 64, wn = (wid & 1) * 64;

    floatx4 acc[4][4] = {};
    gemm_mainloop(Wcat + (size_t)m0 * 1024,
                  xT + ((size_t)b * TT + n0) * HID,
                  aT, bTl, acc, tid);

    const int sec = m0 >> 10;          // 0=q 1=k 2=v (uniform per block)
    const int mo = m0 & 1023;

    if (sec < 2) {
        const float* bias = (sec == 0) ? bqs : bk;
        _Float16* dst = (sec == 0) ? QT : KT;
        _Float16* tr = (_Float16*)smem;     // 128 x 136 halves = 34816 B
        for (int mi = 0; mi < 4; mi++) {
            float bs[4];
            for (int r = 0; r < 4; r++)
                bs[r] = bias[mo + wm + mi * 16 + quad * 4 + r];
            for (int ni = 0; ni < 4; ni++) {
                half4 pk;
                for (int r = 0; r < 4; r++)
                    pk[r] = (_Float16)(acc[mi][ni][r] + bs[r]);
                int tl = wn + ni * 16 + l15;
                int ol = wm + mi * 16 + quad * 4;
                *(half4*)(tr + tl * 136 + ol) = pk;
            }
        }
        __syncthreads();
        int tl = tid >> 1, cb = (tid & 1) * 64;
        for (int ch = 0; ch < 8; ch++) {
            uint4 v = *(uint4*)(tr + tl * 136 + cb + ch * 8);
            *(uint4*)(dst + ((size_t)b * TT + n0 + tl) * HID + mo + cb + ch * 8) = v;
        }
    } else {
        for (int mi = 0; mi < 4; mi++) {
            float bs[4];
            for (int r = 0; r < 4; r++)
                bs[r] = bv[mo + wm + mi * 16 + quad * 4 + r];
            for (int ni = 0; ni < 4; ni++) {
                int t = n0 + wn + ni * 16 + l15;
                for (int r = 0; r < 4; r++) {
                    int o = mo + wm + mi * 16 + quad * 4 + r;
                    Vb[((size_t)b * HID + o) * TT + t] =
                        (_Float16)(acc[mi][ni][r] + bs[r]);
                }
            }
        }
    }
}

// ---------------------------------------------------------------------------
// attention (R9 inner loops). 1-D grid 2048, XCD-clustered: group (hd,b)
// pinned to xcd = (hd+16b)%8; q0 inner so K/V slice is fetched once per XCD.
__global__ __launch_bounds__(256) void attn_kernel(
    const _Float16* __restrict__ QT, const _Float16* __restrict__ KT,
    const _Float16* __restrict__ Vb, const int* __restrict__ mask,
    _Float16* __restrict__ OcT)
{
    __shared__ __align__(16) _Float16 kvbuf[4 * 4096];
    __shared__ __align__(16) _Float16 ps[2 * 4096];  // [qt][q][t] swizzled
    __shared__ __align__(16) float msf[2][64];       // clamp hi bound per t

    const int id = blockIdx.x;
    const int xcd = id & 7, slot = id >> 3;      // slot 0..255
    const int grp = xcd + 8 * (slot >> 2);       // 0..511 = hd + 16*b
    const int q0 = (slot & 3) * 128;
    const int hd = grp & 15, b = grp >> 4;
    const int tid = threadIdx.x;
    const int lane = tid & 63, wid = tid >> 6;
    const int l15 = lane & 15, quad = lane >> 4;

    const _Float16* QTb = QT + ((size_t)b * TT + q0) * HID + hd * 64;
    const _Float16* KTb = KT + (size_t)b * TT * HID + hd * 64;
    const _Float16* Vbb = Vb + ((size_t)b * HID + hd * 64) * TT;
    const int* mb = mask + b * TT;

    const int srow = lane >> 3;                 // 0..7 == row&7
    const int sg = (lane & 7) ^ srow;
    const int pa = quad ^ (l15 & 7);
    const int pz = l15 & 7;

    for (int qt = 0; qt < 2; qt++)
        for (int p = 0; p < 2; p++) {
            int r = p * 32 + wid * 8 + srow;
            gload16(QTb + (size_t)(qt * 64 + r) * HID + sg * 8,
                    kvbuf + qt * 4096 + (p * 32 + wid * 8) * 64);
        }
    __syncthreads();
    half8 bq[2][2];
    for (int qt = 0; qt < 2; qt++) {
        bq[qt][0] = *(half8*)(kvbuf + qt * 4096 + (wid * 16 + l15) * 64 + pa * 8);
        bq[qt][1] = *(half8*)(kvbuf + qt * 4096 + (wid * 16 + l15) * 64 + (pa ^ 4) * 8);
    }
    __syncthreads();

    auto stage = [&](int jcn, int bufn) {
        int t0n = jcn * 64;
        _Float16* kd = kvbuf + bufn * 4096;
        _Float16* vd = kvbuf + (2 + bufn) * 4096;
        for (int p = 0; p < 2; p++) {
            int r = p * 32 + wid * 8 + srow;
            gload16(KTb + (size_t)(t0n + r) * HID + sg * 8,
                    kd + (p * 32 + wid * 8) * 64);
            gload16(Vbb + (size_t)r * TT + t0n + sg * 8,
                    vd + (p * 32 + wid * 8) * 64);
        }
        if (tid < 64) msf[bufn][tid] = mb[t0n + tid] ? SB2 : -SB2;
    };

    stage(0, 0);

    floatx4 oacc[2][4] = {};
    float rs[2] = {0.f, 0.f};
    const float lo = -SB2;

    for (int jc = 0; jc < 8; jc++) {
        const int cur = jc & 1;
        __syncthreads();
        if (jc < 7) stage(jc + 1, 1 - cur);

        const _Float16* ks = kvbuf + cur * 4096;
        const _Float16* vs = kvbuf + (2 + cur) * 4096;

        for (int jt = 0; jt < 4; jt++) {
            half8 ka0 = *(half8*)(ks + (jt * 16 + l15) * 64 + pa * 8);
            half8 ka1 = *(half8*)(ks + (jt * 16 + l15) * 64 + (pa ^ 4) * 8);
            floatx4 hi = *(floatx4*)(&msf[cur][jt * 16 + quad * 4]);
            for (int qt = 0; qt < 2; qt++) {
                floatx4 sc = {0.f, 0.f, 0.f, 0.f};
                sc = __builtin_amdgcn_mfma_f32_16x16x32_f16(ka0, bq[qt][0], sc, 0, 0, 0);
                sc = __builtin_amdgcn_mfma_f32_16x16x32_f16(ka1, bq[qt][1], sc, 0, 0, 0);
                float e0 = __builtin_amdgcn_exp2f(fminf(fmaxf(sc[0], lo), hi[0]));
                float e1 = __builtin_amdgcn_exp2f(fminf(fmaxf(sc[1], lo), hi[1]));
                float e2 = __builtin_amdgcn_exp2f(fminf(fmaxf(sc[2], lo), hi[2]));
                float e3 = __builtin_amdgcn_exp2f(fminf(fmaxf(sc[3], lo), hi[3]));
                rs[qt] += (e0 + e1) + (e2 + e3);
                unsigned uA = __builtin_bit_cast(
                    unsigned, __builtin_amdgcn_cvt_pkrtz(e0, e1));
                unsigned uB = __builtin_bit_cast(
                    unsigned, __builtin_amdgcn_cvt_pkrtz(e2, e3));
                uintx2 uv = {uA, uB};
                half4 pk = __builtin_bit_cast(half4, uv);
                int g = jt * 2 + (quad >> 1);
                *(half4*)(ps + qt * 4096 + (wid * 16 + l15) * 64 + (g ^ pz) * 8 +
                          (quad & 1) * 4) = pk;
            }
        }
        for (int kc = 0; kc < 2; kc++) {
            int g = kc * 4 + quad;
            half8 bv8[4];
            for (int d4 = 0; d4 < 4; d4++)
                bv8[d4] = *(half8*)(vs + (d4 * 16 + l15) * 64 + (g ^ pz) * 8);
            for (int qt = 0; qt < 2; qt++) {
                half8 ap = *(half8*)(ps + qt * 4096 + (wid * 16 + l15) * 64 +
                                     (g ^ pz) * 8);
                for (int d4 = 0; d4 < 4; d4++)
                    oacc[qt][d4] = __builtin_amdgcn_mfma_f32_16x16x32_f16(
                        ap, bv8[d4], oacc[qt][d4], 0, 0, 0);
            }
        }
    }

    for (int qt = 0; qt < 2; qt++) {
        float s = rs[qt];
        s += __shfl_xor(s, 16, 64);
        s += __shfl_xor(s, 32, 64);
        s = 1.0f / s;
        float inv[4];
        for (int r = 0; r < 4; r++) inv[r] = __shfl(s, quad * 4 + r, 64);
        for (int d4 = 0; d4 < 4; d4++)
            for (int r = 0; r < 4; r++) {
                int t = q0 + qt * 64 + wid * 16 + quad * 4 + r;
                int c = hd * 64 + d4 * 16 + l15;
                OcT[((size_t)b * TT + t) * HID + c] =
                    (_Float16)(oacc[qt][d4][r] * inv[r]);
            }
    }
}

// ---------------------------------------------------------------------------
// gemm2. 1-D grid 1024, XCD-clustered like gemm1 (8 m-tiles per group).
__global__ __launch_bounds__(256) void gemm2_kernel(
    const _Float16* __restrict__ Wo16, const _Float16* __restrict__ OcT,
    unsigned* __restrict__ omax)
{
    __shared__ __align__(16) char smem[2 * 128 * 64 * 2];
    _Float16* aT = (_Float16*)smem;
    _Float16* bTl = aT + 128 * 64;

    const int tid = threadIdx.x;
    const int id = blockIdx.x;
    const int xcd = id & 7, slot = id >> 3;      // slot 0..127
    const int grp = xcd + 8 * (slot >> 3);       // 0..127 = n0i + 4*b
    const int m0 = (slot & 7) * 128;
    const int n0 = (grp & 3) * 128;
    const int b = grp >> 2;
    const int lane = tid & 63, wid = tid >> 6;
    const int l15 = lane & 15, quad = lane >> 4;
    const int wm = (wid >> 1) * 64;

    floatx4 acc[4][4] = {};
    gemm_mainloop(Wo16 + (size_t)m0 * 1024,
                  OcT + ((size_t)b * TT + n0) * HID,
                  aT, bTl, acc, tid);

    for (int mi = 0; mi < 4; mi++)
        for (int r = 0; r < 4; r++) {
            float v = acc[mi][0][r];
            for (int ni = 1; ni < 4; ni++) v = fmaxf(v, acc[mi][ni][r]);
            for (int d = 1; d < 16; d <<= 1) v = fmaxf(v, __shfl_xor(v, d, 64));
            if (l15 == 0) {
                int o = m0 + wm + mi * 16 + quad * 4 + r;
                atomicMax(&omax[b * HID + o], fkey(v));
            }
        }
}

__global__ __launch_bounds__(256) void final_kernel(
    const unsigned* __restrict__ omax, const float* __restrict__ bo,
    float* __restrict__ out)
{
    int i = blockIdx.x * 256 + threadIdx.x;   // 0 .. 32767
    out[i] = funkey(omax[i]) + bo[i & 1023];
}

// ---------------------------------------------------------------------------
extern "C" void kernel_launch(void* const* d_in, const int* in_sizes, int n_in,
                              void* d_out, int out_size, void* d_ws, size_t ws_size,
                              hipStream_t stream)
{
    const float* x  = (const float*)d_in[0];
    const int* mask = (const int*)d_in[1];
    const float* Wq = (const float*)d_in[2];
    const float* bq = (const float*)d_in[3];
    const float* Wk = (const float*)d_in[4];
    const float* bk = (const float*)d_in[5];
    const float* Wv = (const float*)d_in[6];
    const float* bv = (const float*)d_in[7];
    const float* Wo = (const float*)d_in[8];
    const float* bo = (const float*)d_in[9];
    float* out = (float*)d_out;

    char* ws = (char*)d_ws;
    _Float16* Wcat = (_Float16*)(ws);                      //   8 MiB (q,k,v,o)
    _Float16* xT   = (_Float16*)(ws + (8ull  << 20));      //  32 MiB
    _Float16* QT   = (_Float16*)(ws + (40ull << 20));      //  32 MiB
    _Float16* KT   = (_Float16*)(ws + (72ull << 20));      //  32 MiB
    _Float16* Vb   = (_Float16*)(ws + (104ull << 20));     //  32 MiB
    _Float16* OcT  = (_Float16*)(ws + (136ull << 20));     //  32 MiB
    unsigned* omax = (unsigned*)(ws + (168ull << 20));     // 128 KiB
    float*    bqs  = (float*)(ws + (168ull << 20) + (128ull << 10)); // 4 KiB

    prep_kernel<<<8324, 256, 0, stream>>>(Wq, Wk, Wv, Wo, Wcat, x, xT, omax,
                                          bq, bqs);
    gemm1_kernel<<<3072, 256, 0, stream>>>(Wcat, bqs, bk, bv, xT, QT, KT, Vb);
    attn_kernel<<<2048, 256, 0, stream>>>(QT, KT, Vb, mask, OcT);
    gemm2_kernel<<<1024, 256, 0, stream>>>(Wcat + (3ull << 20), OcT, omax);
    final_kernel<<<128, 256, 0, stream>>>(omax, bo, out);
}